// Round 2
// baseline (9.713 us; speedup 1.0000x reference)
//
#include <hip/hip_runtime.h>
#include <math.h>

// out[t] = sum_d x[t-d] * w(d),  w(d) = exp(-((d-0.5)-mu)^2/(2 s^2)) / (s*sqrt(2pi))
// Full support |d| <= 8191 (zero-padded), but w underflows to exactly 0.0f
// beyond |d-0.5-mu| ~ 13.2*sigma. Fixed 65-tap unrolled window (|d|<=32) is
// exact whenever R = 13.5|s|+|m|+2 <= 32; a uniform-branch tail loop covers
// larger sigma. All loads (sigma, mu, 65-wide x window) are issued before any
// dependent compute so the two HBM/L2 waits overlap.
#define CAP 32

__global__ void gauss_conv1d(const float* __restrict__ x,
                             const float* __restrict__ sigma,
                             const float* __restrict__ mu,
                             float* __restrict__ out,
                             int T) {
    int t = blockIdx.x * blockDim.x + threadIdx.x;

    // Issue uniform scalar loads first (SMEM path, independent of x loads).
    float s = sigma[0];
    float m = mu[0];

    // Issue the full x window: 65 coalesced global loads, all in flight
    // while sigma/mu resolve. Full unroll -> static indexing -> registers.
    float xv[2 * CAP + 1];
#pragma unroll
    for (int d = -CAP; d <= CAP; ++d) {
        int j = t - d;
        xv[d + CAP] = (j >= 0 && j < T) ? x[j] : 0.0f;
    }

    float inv2s2 = 1.0f / (2.0f * s * s);
    float norm   = 1.0f / (s * sqrtf(6.283185307179586f));
    float rf     = 13.5f * fabsf(s) + fabsf(m) + 2.0f;  // truncation radius

    // 65-tap unrolled dot product, 4 independent accumulator chains.
    float a0 = 0.0f, a1 = 0.0f, a2 = 0.0f, a3 = 0.0f;
#pragma unroll
    for (int i = 0; i < 2 * CAP + 1; i += 4) {
        {
            float u = ((float)(i - CAP) - 0.5f) - m;
            a0 = fmaf(xv[i], __expf(-u * u * inv2s2), a0);
        }
        if (i + 1 < 2 * CAP + 1) {
            float u = ((float)(i + 1 - CAP) - 0.5f) - m;
            a1 = fmaf(xv[i + 1], __expf(-u * u * inv2s2), a1);
        }
        if (i + 2 < 2 * CAP + 1) {
            float u = ((float)(i + 2 - CAP) - 0.5f) - m;
            a2 = fmaf(xv[i + 2], __expf(-u * u * inv2s2), a2);
        }
        if (i + 3 < 2 * CAP + 1) {
            float u = ((float)(i + 3 - CAP) - 0.5f) - m;
            a3 = fmaf(xv[i + 3], __expf(-u * u * inv2s2), a3);
        }
    }
    float acc = (a0 + a1) + (a2 + a3);

    // General-sigma tail (uniform branch; skipped when R <= CAP, e.g. sigma=1).
    if (rf >= (float)CAP) {
        int R = (rf >= 8191.0f) ? 8191 : ((int)rf + 1);
        for (int d = CAP + 1; d <= R; ++d) {
            int j1 = t - d;   // positive-d tap
            int j2 = t + d;   // negative-d tap
            float u1 = ((float)d - 0.5f) - m;
            float u2 = ((float)(-d) - 0.5f) - m;
            if (j1 >= 0 && j1 < T) acc = fmaf(x[j1], __expf(-u1 * u1 * inv2s2), acc);
            if (j2 >= 0 && j2 < T) acc = fmaf(x[j2], __expf(-u2 * u2 * inv2s2), acc);
        }
    }

    if (t < T) out[t] = acc * norm;
}

extern "C" void kernel_launch(void* const* d_in, const int* in_sizes, int n_in,
                              void* d_out, int out_size, void* d_ws, size_t ws_size,
                              hipStream_t stream) {
    const float* x     = (const float*)d_in[0];
    const float* sigma = (const float*)d_in[1];
    const float* mu    = (const float*)d_in[2];
    float* out = (float*)d_out;
    int T = in_sizes[0];

    const int block = 256;
    const int grid  = (T + block - 1) / block;  // 64 blocks at T=16384
    gauss_conv1d<<<grid, block, 0, stream>>>(x, sigma, mu, out, T);
}